// Round 1
// baseline (1322.383 us; speedup 1.0000x reference)
//
#include <hip/hip_runtime.h>

#define NVOX 200000
#define KOFF 27
#define CIN 16
#define CMID 32
#define COUT 32
#define EPSBN 1e-3f

// ws layout (bytes):
//   [0, 21,600,000)            gather int32[NVOX*KOFF]  (-1 = no neighbor)
//   [21,600,000, 47,200,000)   x1 float[NVOX*CMID]      (conv1 pre-BN output)
//   [47,200,000, +1KB)         stats floats:
//      +0   sum1[32], sq1[32]
//      +64  scale1[32], shift1[32]
//      +128 sum2[32], sq2[32]
//      +192 scale2[32], shift2[32]

__global__ __launch_bounds__(256) void k_init(int* __restrict__ gather,
                                              float* __restrict__ stats) {
  int t = blockIdx.x * 256 + threadIdx.x;
  int stride = gridDim.x * 256;
  const int total = NVOX * KOFF;
  for (int i = t; i < total; i += stride) gather[i] = -1;
  if (t < 256) stats[t] = 0.f;
}

__global__ __launch_bounds__(256) void k_build(const int* __restrict__ rule_in,
                                               const int* __restrict__ rule_out,
                                               int* __restrict__ gather) {
  int e = blockIdx.x * 256 + threadIdx.x;
  if (e >= KOFF * NVOX) return;
  int k = e / NVOX;  // rule arrays are [K][N] row-major
  int dst = rule_out[e];
  if (dst < NVOX) gather[dst * KOFF + k] = rule_in[e];
}

// conv1: feats[N,16] @ W1[27,16,32], gather-form, pre-BN output to x1
__global__ __launch_bounds__(256) void k_conv1(const float* __restrict__ feats,
                                               const float* __restrict__ W1,
                                               const int* __restrict__ gather,
                                               float* __restrict__ x1) {
  int j = blockIdx.x * 256 + threadIdx.x;
  if (j >= NVOX) return;
  float acc[CMID];
#pragma unroll
  for (int o = 0; o < CMID; ++o) acc[o] = 0.f;
#pragma unroll 1
  for (int k = 0; k < KOFF; ++k) {
    int src = gather[j * KOFF + k];
    float m = (src >= 0) ? 1.0f : 0.0f;
    int s = (src >= 0) ? src : 0;
    const float4* fp = (const float4*)(feats + (size_t)s * CIN);
    float4 a = fp[0], b = fp[1], c4 = fp[2], d = fp[3];
    float f[CIN] = {a.x, a.y, a.z, a.w, b.x, b.y, b.z, b.w,
                    c4.x, c4.y, c4.z, c4.w, d.x, d.y, d.z, d.w};
    const float* __restrict__ Wk = W1 + k * (CIN * CMID);
#pragma unroll
    for (int c = 0; c < CIN; ++c) {
      float fv = f[c] * m;
#pragma unroll
      for (int o = 0; o < CMID; ++o)
        acc[o] = fmaf(fv, Wk[c * CMID + o], acc[o]);
    }
  }
  float4* xp = (float4*)(x1 + (size_t)j * CMID);
#pragma unroll
  for (int o = 0; o < CMID / 4; ++o)
    xp[o] = make_float4(acc[4 * o], acc[4 * o + 1], acc[4 * o + 2], acc[4 * o + 3]);
}

// per-channel sum + sumsq over x[N,32] -> sums[0:32]=sum, sums[32:64]=sumsq
__global__ __launch_bounds__(256) void k_stats(const float* __restrict__ x,
                                               float* __restrict__ sums) {
  int tid = blockIdx.x * 256 + threadIdx.x;
  int stride = gridDim.x * 256;
  float s[32], q[32];
#pragma unroll
  for (int o = 0; o < 32; ++o) { s[o] = 0.f; q[o] = 0.f; }
  for (int j = tid; j < NVOX; j += stride) {
    const float4* xp = (const float4*)(x + (size_t)j * 32);
#pragma unroll
    for (int o8 = 0; o8 < 8; ++o8) {
      float4 v = xp[o8];
      s[4 * o8 + 0] += v.x; q[4 * o8 + 0] += v.x * v.x;
      s[4 * o8 + 1] += v.y; q[4 * o8 + 1] += v.y * v.y;
      s[4 * o8 + 2] += v.z; q[4 * o8 + 2] += v.z * v.z;
      s[4 * o8 + 3] += v.w; q[4 * o8 + 3] += v.w * v.w;
    }
  }
#pragma unroll
  for (int o = 0; o < 32; ++o) {
    float vs = s[o], vq = q[o];
#pragma unroll
    for (int msk = 1; msk < 64; msk <<= 1) {
      vs += __shfl_xor(vs, msk, 64);
      vq += __shfl_xor(vq, msk, 64);
    }
    if ((threadIdx.x & 63) == 0) {
      atomicAdd(&sums[o], vs);
      atomicAdd(&sums[32 + o], vq);
    }
  }
}

__global__ void k_finalize(const float* __restrict__ sums,
                           const float* __restrict__ gamma,
                           const float* __restrict__ beta,
                           float* __restrict__ ss) {
  int o = threadIdx.x;
  if (o < 32) {
    const float inv_n = 1.0f / (float)NVOX;
    float mu = sums[o] * inv_n;
    float var = sums[32 + o] * inv_n - mu * mu;
    float sc = gamma[o] * rsqrtf(var + EPSBN);
    ss[o] = sc;
    ss[32 + o] = beta[o] - mu * sc;
  }
}

// conv2: relu(bn1(x1)) gathered on the fly, @ W2[27,32,32], pre-BN out
__global__ __launch_bounds__(256) void k_conv2(const float* __restrict__ x1,
                                               const float* __restrict__ W2,
                                               const int* __restrict__ gather,
                                               const float* __restrict__ ss,
                                               float* __restrict__ out) {
  int j = blockIdx.x * 256 + threadIdx.x;
  if (j >= NVOX) return;
  float acc[COUT];
#pragma unroll
  for (int o = 0; o < COUT; ++o) acc[o] = 0.f;
#pragma unroll 1
  for (int k = 0; k < KOFF; ++k) {
    int src = gather[j * KOFF + k];
    float m = (src >= 0) ? 1.0f : 0.0f;
    int s = (src >= 0) ? src : 0;
    const float4* fp = (const float4*)(x1 + (size_t)s * CMID);
    float y[CMID];
#pragma unroll
    for (int c4i = 0; c4i < CMID / 4; ++c4i) {
      float4 v = fp[c4i];
      int c = 4 * c4i;
      y[c + 0] = fmaxf(fmaf(v.x, ss[c + 0], ss[32 + c + 0]), 0.f) * m;
      y[c + 1] = fmaxf(fmaf(v.y, ss[c + 1], ss[32 + c + 1]), 0.f) * m;
      y[c + 2] = fmaxf(fmaf(v.z, ss[c + 2], ss[32 + c + 2]), 0.f) * m;
      y[c + 3] = fmaxf(fmaf(v.w, ss[c + 3], ss[32 + c + 3]), 0.f) * m;
    }
    const float* __restrict__ Wk = W2 + k * (CMID * COUT);
#pragma unroll
    for (int c = 0; c < CMID; ++c) {
      float fv = y[c];
#pragma unroll
      for (int o = 0; o < COUT; ++o)
        acc[o] = fmaf(fv, Wk[c * COUT + o], acc[o]);
    }
  }
  float4* xp = (float4*)(out + (size_t)j * COUT);
#pragma unroll
  for (int o = 0; o < COUT / 4; ++o)
    xp[o] = make_float4(acc[4 * o], acc[4 * o + 1], acc[4 * o + 2], acc[4 * o + 3]);
}

__global__ __launch_bounds__(256) void k_bn2(float* __restrict__ out,
                                             const float* __restrict__ ss) {
  int t = blockIdx.x * 256 + threadIdx.x;
  if (t >= NVOX * COUT / 4) return;
  float4* p = (float4*)out + t;
  int c = (t & 7) * 4;
  float4 v = *p;
  v.x = fmaxf(fmaf(v.x, ss[c + 0], ss[32 + c + 0]), 0.f);
  v.y = fmaxf(fmaf(v.y, ss[c + 1], ss[32 + c + 1]), 0.f);
  v.z = fmaxf(fmaf(v.z, ss[c + 2], ss[32 + c + 2]), 0.f);
  v.w = fmaxf(fmaf(v.w, ss[c + 3], ss[32 + c + 3]), 0.f);
  *p = v;
}

extern "C" void kernel_launch(void* const* d_in, const int* in_sizes, int n_in,
                              void* d_out, int out_size, void* d_ws, size_t ws_size,
                              hipStream_t stream) {
  const float* feats  = (const float*)d_in[0];
  const float* W1     = (const float*)d_in[1];
  const float* gamma1 = (const float*)d_in[2];
  const float* beta1  = (const float*)d_in[3];
  const float* W2     = (const float*)d_in[4];
  const float* gamma2 = (const float*)d_in[5];
  const float* beta2  = (const float*)d_in[6];
  const int* rule_in  = (const int*)d_in[7];
  const int* rule_out = (const int*)d_in[8];
  float* out = (float*)d_out;

  int*   gather = (int*)d_ws;
  float* x1     = (float*)((char*)d_ws + 21600000);
  float* stats  = (float*)((char*)d_ws + 47200000);
  // stats: [0:64] sums1, [64:128] ss1, [128:192] sums2, [192:256] ss2

  k_init<<<2048, 256, 0, stream>>>(gather, stats);
  k_build<<<(KOFF * NVOX + 255) / 256, 256, 0, stream>>>(rule_in, rule_out, gather);
  k_conv1<<<(NVOX + 255) / 256, 256, 0, stream>>>(feats, W1, gather, x1);
  k_stats<<<256, 256, 0, stream>>>(x1, stats);
  k_finalize<<<1, 64, 0, stream>>>(stats, gamma1, beta1, stats + 64);
  k_conv2<<<(NVOX + 255) / 256, 256, 0, stream>>>(x1, W2, gather, stats + 64, out);
  k_stats<<<256, 256, 0, stream>>>(out, stats + 128);
  k_finalize<<<1, 64, 0, stream>>>(stats + 128, gamma2, beta2, stats + 192);
  k_bn2<<<(NVOX * COUT / 4 + 255) / 256, 256, 0, stream>>>(out, stats + 192);
}

// Round 2
// 775.716 us; speedup vs baseline: 1.7047x; 1.7047x over previous
//
#include <hip/hip_runtime.h>

#define NVOX 200000
#define KOFF 27
#define CIN 16
#define CMID 32
#define COUT 32
#define EPSBN 1e-3f

// ws layout (bytes):
//   [0, 21,600,000)            gather int32[NVOX*KOFF]  (-1 = no neighbor)
//   [21,600,000, 47,200,000)   x1 float[NVOX*CMID]      (conv1 pre-BN output)
//   [47,200,000, +1KB)         stats floats:
//      +0   sum1[32], sq1[32]
//      +64  scale1[32], shift1[32]
//      +128 sum2[32], sq2[32]
//      +192 scale2[32], shift2[32]

__global__ __launch_bounds__(256) void k_init(int* __restrict__ gather,
                                              float* __restrict__ stats) {
  int t = blockIdx.x * 256 + threadIdx.x;
  int stride = gridDim.x * 256;
  const int total = NVOX * KOFF;
  for (int i = t; i < total; i += stride) gather[i] = -1;
  if (t < 256) stats[t] = 0.f;
}

__global__ __launch_bounds__(256) void k_build(const int* __restrict__ rule_in,
                                               const int* __restrict__ rule_out,
                                               int* __restrict__ gather) {
  int e = blockIdx.x * 256 + threadIdx.x;
  if (e >= KOFF * NVOX) return;
  int k = e / NVOX;  // rule arrays are [K][N] row-major
  int dst = rule_out[e];
  if (dst < NVOX) gather[dst * KOFF + k] = rule_in[e];
}

// conv1: feats[N,16] @ W1[27,16,32], gather-form, pre-BN output to x1.
// Fused: per-channel sum/sumsq reduction into gsums[0:32]/[32:64].
__global__ __launch_bounds__(256) void k_conv1s(const float* __restrict__ feats,
                                                const float* __restrict__ W1,
                                                const int* __restrict__ gather,
                                                float* __restrict__ x1,
                                                float* __restrict__ gsums) {
  __shared__ float lsum[64];
  if (threadIdx.x < 64) lsum[threadIdx.x] = 0.f;
  __syncthreads();

  int j = blockIdx.x * 256 + threadIdx.x;
  bool valid = j < NVOX;
  int jj = valid ? j : NVOX - 1;
  float vmask = valid ? 1.f : 0.f;

  float acc[CMID];
#pragma unroll
  for (int o = 0; o < CMID; ++o) acc[o] = 0.f;
#pragma unroll 1
  for (int k = 0; k < KOFF; ++k) {
    int src = gather[jj * KOFF + k];
    float m = (src >= 0) ? 1.0f : 0.0f;
    int s = (src >= 0) ? src : 0;
    const float4* fp = (const float4*)(feats + (size_t)s * CIN);
    float4 a = fp[0], b = fp[1], c4 = fp[2], d = fp[3];
    float f[CIN] = {a.x, a.y, a.z, a.w, b.x, b.y, b.z, b.w,
                    c4.x, c4.y, c4.z, c4.w, d.x, d.y, d.z, d.w};
    const float* __restrict__ Wk = W1 + k * (CIN * CMID);
#pragma unroll
    for (int c = 0; c < CIN; ++c) {
      float fv = f[c] * m;
#pragma unroll
      for (int o = 0; o < CMID; ++o)
        acc[o] = fmaf(fv, Wk[c * CMID + o], acc[o]);
    }
  }

  // fused BN-stats: butterfly reduce each channel over the 64-lane wave
  int lane = threadIdx.x & 63;
  float r_s = 0.f, r_q = 0.f;
#pragma unroll
  for (int o = 0; o < CMID; ++o) {
    float vs = acc[o] * vmask;
    float vq = vs * vs;
#pragma unroll
    for (int msk = 1; msk < 64; msk <<= 1) {
      vs += __shfl_xor(vs, msk, 64);
      vq += __shfl_xor(vq, msk, 64);
    }
    if (lane == o) { r_s = vs; r_q = vq; }
  }
  if (lane < CMID) {
    atomicAdd(&lsum[lane], r_s);
    atomicAdd(&lsum[32 + lane], r_q);
  }

  if (valid) {
    float4* xp = (float4*)(x1 + (size_t)j * CMID);
#pragma unroll
    for (int o = 0; o < CMID / 4; ++o)
      xp[o] = make_float4(acc[4 * o], acc[4 * o + 1], acc[4 * o + 2], acc[4 * o + 3]);
  }

  __syncthreads();
  if (threadIdx.x < 64) atomicAdd(&gsums[threadIdx.x], lsum[threadIdx.x]);
}

__global__ void k_finalize(const float* __restrict__ sums,
                           const float* __restrict__ gamma,
                           const float* __restrict__ beta,
                           float* __restrict__ ss) {
  int o = threadIdx.x;
  if (o < 32) {
    const float inv_n = 1.0f / (float)NVOX;
    float mu = sums[o] * inv_n;
    float var = sums[32 + o] * inv_n - mu * mu;
    float sc = gamma[o] * rsqrtf(var + EPSBN);
    ss[o] = sc;
    ss[32 + o] = beta[o] - mu * sc;
  }
}

// conv2: relu(bn1(x1)) gathered on the fly, @ W2[27,32,32], pre-BN out.
// Fused: per-channel sum/sumsq reduction into gsums.
__global__ __launch_bounds__(256) void k_conv2s(const float* __restrict__ x1,
                                                const float* __restrict__ W2,
                                                const int* __restrict__ gather,
                                                const float* __restrict__ ss,
                                                float* __restrict__ out,
                                                float* __restrict__ gsums) {
  __shared__ float lsum[64];
  if (threadIdx.x < 64) lsum[threadIdx.x] = 0.f;
  __syncthreads();

  int j = blockIdx.x * 256 + threadIdx.x;
  bool valid = j < NVOX;
  int jj = valid ? j : NVOX - 1;
  float vmask = valid ? 1.f : 0.f;

  float acc[COUT];
#pragma unroll
  for (int o = 0; o < COUT; ++o) acc[o] = 0.f;
#pragma unroll 1
  for (int k = 0; k < KOFF; ++k) {
    int src = gather[jj * KOFF + k];
    float m = (src >= 0) ? 1.0f : 0.0f;
    int s = (src >= 0) ? src : 0;
    const float4* fp = (const float4*)(x1 + (size_t)s * CMID);
    float y[CMID];
#pragma unroll
    for (int c4i = 0; c4i < CMID / 4; ++c4i) {
      float4 v = fp[c4i];
      int c = 4 * c4i;
      y[c + 0] = fmaxf(fmaf(v.x, ss[c + 0], ss[32 + c + 0]), 0.f) * m;
      y[c + 1] = fmaxf(fmaf(v.y, ss[c + 1], ss[32 + c + 1]), 0.f) * m;
      y[c + 2] = fmaxf(fmaf(v.z, ss[c + 2], ss[32 + c + 2]), 0.f) * m;
      y[c + 3] = fmaxf(fmaf(v.w, ss[c + 3], ss[32 + c + 3]), 0.f) * m;
    }
    const float* __restrict__ Wk = W2 + k * (CMID * COUT);
#pragma unroll
    for (int c = 0; c < CMID; ++c) {
      float fv = y[c];
#pragma unroll
      for (int o = 0; o < COUT; ++o)
        acc[o] = fmaf(fv, Wk[c * COUT + o], acc[o]);
    }
  }

  int lane = threadIdx.x & 63;
  float r_s = 0.f, r_q = 0.f;
#pragma unroll
  for (int o = 0; o < COUT; ++o) {
    float vs = acc[o] * vmask;
    float vq = vs * vs;
#pragma unroll
    for (int msk = 1; msk < 64; msk <<= 1) {
      vs += __shfl_xor(vs, msk, 64);
      vq += __shfl_xor(vq, msk, 64);
    }
    if (lane == o) { r_s = vs; r_q = vq; }
  }
  if (lane < COUT) {
    atomicAdd(&lsum[lane], r_s);
    atomicAdd(&lsum[32 + lane], r_q);
  }

  if (valid) {
    float4* xp = (float4*)(out + (size_t)j * COUT);
#pragma unroll
    for (int o = 0; o < COUT / 4; ++o)
      xp[o] = make_float4(acc[4 * o], acc[4 * o + 1], acc[4 * o + 2], acc[4 * o + 3]);
  }

  __syncthreads();
  if (threadIdx.x < 64) atomicAdd(&gsums[threadIdx.x], lsum[threadIdx.x]);
}

__global__ __launch_bounds__(256) void k_bn2(float* __restrict__ out,
                                             const float* __restrict__ ss) {
  int t = blockIdx.x * 256 + threadIdx.x;
  if (t >= NVOX * COUT / 4) return;
  float4* p = (float4*)out + t;
  int c = (t & 7) * 4;
  float4 v = *p;
  v.x = fmaxf(fmaf(v.x, ss[c + 0], ss[32 + c + 0]), 0.f);
  v.y = fmaxf(fmaf(v.y, ss[c + 1], ss[32 + c + 1]), 0.f);
  v.z = fmaxf(fmaf(v.z, ss[c + 2], ss[32 + c + 2]), 0.f);
  v.w = fmaxf(fmaf(v.w, ss[c + 3], ss[32 + c + 3]), 0.f);
  *p = v;
}

extern "C" void kernel_launch(void* const* d_in, const int* in_sizes, int n_in,
                              void* d_out, int out_size, void* d_ws, size_t ws_size,
                              hipStream_t stream) {
  const float* feats  = (const float*)d_in[0];
  const float* W1     = (const float*)d_in[1];
  const float* gamma1 = (const float*)d_in[2];
  const float* beta1  = (const float*)d_in[3];
  const float* W2     = (const float*)d_in[4];
  const float* gamma2 = (const float*)d_in[5];
  const float* beta2  = (const float*)d_in[6];
  const int* rule_in  = (const int*)d_in[7];
  const int* rule_out = (const int*)d_in[8];
  float* out = (float*)d_out;

  int*   gather = (int*)d_ws;
  float* x1     = (float*)((char*)d_ws + 21600000);
  float* stats  = (float*)((char*)d_ws + 47200000);
  // stats: [0:64] sums1, [64:128] ss1, [128:192] sums2, [192:256] ss2

  const int grid_rows = (NVOX + 255) / 256;

  k_init<<<2048, 256, 0, stream>>>(gather, stats);
  k_build<<<(KOFF * NVOX + 255) / 256, 256, 0, stream>>>(rule_in, rule_out, gather);
  k_conv1s<<<grid_rows, 256, 0, stream>>>(feats, W1, gather, x1, stats);
  k_finalize<<<1, 64, 0, stream>>>(stats, gamma1, beta1, stats + 64);
  k_conv2s<<<grid_rows, 256, 0, stream>>>(x1, W2, gather, stats + 64, out, stats + 128);
  k_finalize<<<1, 64, 0, stream>>>(stats + 128, gamma2, beta2, stats + 192);
  k_bn2<<<(NVOX * COUT / 4 + 255) / 256, 256, 0, stream>>>(out, stats + 192);
}

// Round 3
// 644.383 us; speedup vs baseline: 2.0522x; 1.2038x over previous
//
#include <hip/hip_runtime.h>

#define NVOX 200000
#define KOFF 27
#define CIN 16
#define CMID 32
#define COUT 32
#define EPSBN 1e-3f

// ws layout (bytes):
//   [0, 21,600,000)            gatherT int32[KOFF][NVOX]  (-1 = no neighbor)
//   [21,600,000, 47,200,000)   x1 float[NVOX*CMID]  (conv1 out; later BN1+ReLU applied in place)
//   [47,200,000, +1KB)         stats floats:
//      +0   sum1[32], sq1[32];  +64  scale1[32], shift1[32]
//      +128 sum2[32], sq2[32];  +192 scale2[32], shift2[32]

__global__ __launch_bounds__(256) void k_init(int* __restrict__ gather,
                                              float* __restrict__ stats) {
  int t = blockIdx.x * 256 + threadIdx.x;
  int stride = gridDim.x * 256;
  const int total = NVOX * KOFF;
  for (int i = t; i < total; i += stride) gather[i] = -1;
  if (t < 256) stats[t] = 0.f;
}

// gatherT[k][dst] = src.  rule arrays are [K][N] row-major; rule_out sorted
// within each k => writes are near-sequential.
__global__ __launch_bounds__(256) void k_build(const int* __restrict__ rule_in,
                                               const int* __restrict__ rule_out,
                                               int* __restrict__ gatherT) {
  int e = blockIdx.x * 256 + threadIdx.x;
  if (e >= KOFF * NVOX) return;
  int k = e / NVOX;
  int dst = rule_out[e];
  if (dst < NVOX) gatherT[k * NVOX + dst] = rule_in[e];
}

// conv1: feats[N,16] @ W1[27,16,32] (gather form, prefetched), pre-BN out to x1.
// Fused BN1 stats into gsums[0:32]/[32:64].
__global__ __launch_bounds__(256) void k_conv1s(const float* __restrict__ feats,
                                                const float* __restrict__ W1,
                                                const int* __restrict__ gatherT,
                                                float* __restrict__ x1,
                                                float* __restrict__ gsums) {
  __shared__ float lsum[64];
  if (threadIdx.x < 64) lsum[threadIdx.x] = 0.f;
  __syncthreads();

  int j = blockIdx.x * 256 + threadIdx.x;
  bool valid = j < NVOX;
  int jj = valid ? j : NVOX - 1;
  float vmask = valid ? 1.f : 0.f;

  float acc[CMID];
#pragma unroll
  for (int o = 0; o < CMID; ++o) acc[o] = 0.f;

  // prefetch k=0
  int src_n = gatherT[jj];
  float4 r0, r1, r2, r3;
  {
    int s = (src_n >= 0) ? src_n : 0;
    const float4* fp = (const float4*)(feats + (size_t)s * CIN);
    r0 = fp[0]; r1 = fp[1]; r2 = fp[2]; r3 = fp[3];
  }

#pragma unroll 1
  for (int k = 0; k < KOFF; ++k) {
    float m = (src_n >= 0) ? 1.0f : 0.0f;
    float f[CIN] = {r0.x * m, r0.y * m, r0.z * m, r0.w * m,
                    r1.x * m, r1.y * m, r1.z * m, r1.w * m,
                    r2.x * m, r2.y * m, r2.z * m, r2.w * m,
                    r3.x * m, r3.y * m, r3.z * m, r3.w * m};
    // prefetch k+1 (k=26: harmless re-load of k=26's row, unused)
    int kn = (k < KOFF - 1) ? (k + 1) : k;
    int src2 = gatherT[kn * NVOX + jj];
    {
      int s2 = (src2 >= 0) ? src2 : 0;
      const float4* fp2 = (const float4*)(feats + (size_t)s2 * CIN);
      r0 = fp2[0]; r1 = fp2[1]; r2 = fp2[2]; r3 = fp2[3];
    }
    const float* __restrict__ Wk = W1 + k * (CIN * CMID);
#pragma unroll
    for (int c = 0; c < CIN; ++c) {
      float fv = f[c];
#pragma unroll
      for (int o = 0; o < CMID; ++o)
        acc[o] = fmaf(fv, Wk[c * CMID + o], acc[o]);
    }
    src_n = src2;
  }

  // fused BN-stats: butterfly reduce each channel over the 64-lane wave
  int lane = threadIdx.x & 63;
  float r_s = 0.f, r_q = 0.f;
#pragma unroll
  for (int o = 0; o < CMID; ++o) {
    float vs = acc[o] * vmask;
    float vq = vs * vs;
#pragma unroll
    for (int msk = 1; msk < 64; msk <<= 1) {
      vs += __shfl_xor(vs, msk, 64);
      vq += __shfl_xor(vq, msk, 64);
    }
    if (lane == o) { r_s = vs; r_q = vq; }
  }
  if (lane < CMID) {
    atomicAdd(&lsum[lane], r_s);
    atomicAdd(&lsum[32 + lane], r_q);
  }

  if (valid) {
    float4* xp = (float4*)(x1 + (size_t)j * CMID);
#pragma unroll
    for (int o = 0; o < CMID / 4; ++o)
      xp[o] = make_float4(acc[4 * o], acc[4 * o + 1], acc[4 * o + 2], acc[4 * o + 3]);
  }

  __syncthreads();
  if (threadIdx.x < 64) atomicAdd(&gsums[threadIdx.x], lsum[threadIdx.x]);
}

__global__ void k_finalize(const float* __restrict__ sums,
                           const float* __restrict__ gamma,
                           const float* __restrict__ beta,
                           float* __restrict__ ss) {
  int o = threadIdx.x;
  if (o < 32) {
    const float inv_n = 1.0f / (float)NVOX;
    float mu = sums[o] * inv_n;
    float var = sums[32 + o] * inv_n - mu * mu;
    float sc = gamma[o] * rsqrtf(var + EPSBN);
    ss[o] = sc;
    ss[32 + o] = beta[o] - mu * sc;
  }
}

// elementwise BN1+ReLU applied in place to x1
__global__ __launch_bounds__(256) void k_bnrelu(float* __restrict__ x,
                                                const float* __restrict__ ss) {
  int t = blockIdx.x * 256 + threadIdx.x;
  if (t >= NVOX * CMID / 4) return;
  float4* p = (float4*)x + t;
  int c = (t & 7) * 4;
  float4 v = *p;
  v.x = fmaxf(fmaf(v.x, ss[c + 0], ss[32 + c + 0]), 0.f);
  v.y = fmaxf(fmaf(v.y, ss[c + 1], ss[32 + c + 1]), 0.f);
  v.z = fmaxf(fmaf(v.z, ss[c + 2], ss[32 + c + 2]), 0.f);
  v.w = fmaxf(fmaf(v.w, ss[c + 3], ss[32 + c + 3]), 0.f);
  *p = v;
}

// conv2: x1(post-BN) gathered w/ prefetch, @ W2[27,32,32], pre-BN out.
// Fused BN2 stats into gsums.
__global__ __launch_bounds__(256) void k_conv2s(const float* __restrict__ x1,
                                                const float* __restrict__ W2,
                                                const int* __restrict__ gatherT,
                                                float* __restrict__ out,
                                                float* __restrict__ gsums) {
  __shared__ float lsum[64];
  if (threadIdx.x < 64) lsum[threadIdx.x] = 0.f;
  __syncthreads();

  int j = blockIdx.x * 256 + threadIdx.x;
  bool valid = j < NVOX;
  int jj = valid ? j : NVOX - 1;
  float vmask = valid ? 1.f : 0.f;

  float acc[COUT];
#pragma unroll
  for (int o = 0; o < COUT; ++o) acc[o] = 0.f;

  int src_n = gatherT[jj];
  float4 r[8];
  {
    int s = (src_n >= 0) ? src_n : 0;
    const float4* fp = (const float4*)(x1 + (size_t)s * CMID);
#pragma unroll
    for (int i = 0; i < 8; ++i) r[i] = fp[i];
  }

#pragma unroll 1
  for (int k = 0; k < KOFF; ++k) {
    float m = (src_n >= 0) ? 1.0f : 0.0f;
    float y[CMID];
#pragma unroll
    for (int i = 0; i < 8; ++i) {
      y[4 * i + 0] = r[i].x * m;
      y[4 * i + 1] = r[i].y * m;
      y[4 * i + 2] = r[i].z * m;
      y[4 * i + 3] = r[i].w * m;
    }
    int kn = (k < KOFF - 1) ? (k + 1) : k;
    int src2 = gatherT[kn * NVOX + jj];
    {
      int s2 = (src2 >= 0) ? src2 : 0;
      const float4* fp2 = (const float4*)(x1 + (size_t)s2 * CMID);
#pragma unroll
      for (int i = 0; i < 8; ++i) r[i] = fp2[i];
    }
    const float* __restrict__ Wk = W2 + k * (CMID * COUT);
#pragma unroll
    for (int c = 0; c < CMID; ++c) {
      float fv = y[c];
#pragma unroll
      for (int o = 0; o < COUT; ++o)
        acc[o] = fmaf(fv, Wk[c * COUT + o], acc[o]);
    }
    src_n = src2;
  }

  int lane = threadIdx.x & 63;
  float r_s = 0.f, r_q = 0.f;
#pragma unroll
  for (int o = 0; o < COUT; ++o) {
    float vs = acc[o] * vmask;
    float vq = vs * vs;
#pragma unroll
    for (int msk = 1; msk < 64; msk <<= 1) {
      vs += __shfl_xor(vs, msk, 64);
      vq += __shfl_xor(vq, msk, 64);
    }
    if (lane == o) { r_s = vs; r_q = vq; }
  }
  if (lane < COUT) {
    atomicAdd(&lsum[lane], r_s);
    atomicAdd(&lsum[32 + lane], r_q);
  }

  if (valid) {
    float4* xp = (float4*)(out + (size_t)j * COUT);
#pragma unroll
    for (int o = 0; o < COUT / 4; ++o)
      xp[o] = make_float4(acc[4 * o], acc[4 * o + 1], acc[4 * o + 2], acc[4 * o + 3]);
  }

  __syncthreads();
  if (threadIdx.x < 64) atomicAdd(&gsums[threadIdx.x], lsum[threadIdx.x]);
}

extern "C" void kernel_launch(void* const* d_in, const int* in_sizes, int n_in,
                              void* d_out, int out_size, void* d_ws, size_t ws_size,
                              hipStream_t stream) {
  const float* feats  = (const float*)d_in[0];
  const float* W1     = (const float*)d_in[1];
  const float* gamma1 = (const float*)d_in[2];
  const float* beta1  = (const float*)d_in[3];
  const float* W2     = (const float*)d_in[4];
  const float* gamma2 = (const float*)d_in[5];
  const float* beta2  = (const float*)d_in[6];
  const int* rule_in  = (const int*)d_in[7];
  const int* rule_out = (const int*)d_in[8];
  float* out = (float*)d_out;

  int*   gatherT = (int*)d_ws;
  float* x1      = (float*)((char*)d_ws + 21600000);
  float* stats   = (float*)((char*)d_ws + 47200000);
  // stats: [0:64] sums1, [64:128] ss1, [128:192] sums2, [192:256] ss2

  const int grid_rows = (NVOX + 255) / 256;

  k_init<<<2048, 256, 0, stream>>>(gatherT, stats);
  k_build<<<(KOFF * NVOX + 255) / 256, 256, 0, stream>>>(rule_in, rule_out, gatherT);
  k_conv1s<<<grid_rows, 256, 0, stream>>>(feats, W1, gatherT, x1, stats);
  k_finalize<<<1, 64, 0, stream>>>(stats, gamma1, beta1, stats + 64);
  k_bnrelu<<<(NVOX * CMID / 4 + 255) / 256, 256, 0, stream>>>(x1, stats + 64);
  k_conv2s<<<grid_rows, 256, 0, stream>>>(x1, W2, gatherT, out, stats + 128);
  k_finalize<<<1, 64, 0, stream>>>(stats + 128, gamma2, beta2, stats + 192);
  k_bnrelu<<<(NVOX * COUT / 4 + 255) / 256, 256, 0, stream>>>(out, stats + 192);
}

// Round 4
// 227.651 us; speedup vs baseline: 5.8088x; 2.8306x over previous
//
#include <hip/hip_runtime.h>

#define NVOX 200000
#define KOFF 27
#define CIN 16
#define CMID 32
#define COUT 32
#define EPSBN 1e-3f
#define NPAIR 14  // conv1 packs 2 offsets per MFMA K=32

typedef _Float16 f16x8 __attribute__((ext_vector_type(8)));
typedef _Float16 f16x4 __attribute__((ext_vector_type(4)));
typedef float f32x4 __attribute__((ext_vector_type(4)));

// ws layout (bytes):
//   [0, 21,600,000)              gatherT int32[KOFF][NVOX] (-1 = none)
//   [21,600,000, 34,400,064)     x1h fp16[(NVOX+1)][32]  (conv1 out; BN1+ReLU in place; row NVOX = zeros)
//   [34,400,064, 40,800,096)     featsh fp16[(NVOX+1)][16] (row NVOX = zeros)
//   [40,800,096, 40,828,768)     WB1 fp16[14*1024]  B-fragment-ordered W1 (2 offsets/pair, zero-padded)
//   [40,828,768, 40,884,064)     WB2 fp16[27*1024]  B-fragment-ordered W2
//   [40,884,064, +1KB)           stats: sums1[64] | ss1[64] | sums2[64] | ss2[64]
#define OFF_X1H 21600000
#define OFF_FH  34400064
#define OFF_WB1 40800096
#define OFF_WB2 40828768
#define OFF_ST  40884064

__global__ __launch_bounds__(256) void k_init(const float* __restrict__ feats,
                                              int* __restrict__ gatherT,
                                              _Float16* __restrict__ featsh,
                                              _Float16* __restrict__ x1h,
                                              float* __restrict__ stats) {
  int t = blockIdx.x * 256 + threadIdx.x;
  int stride = gridDim.x * 256;
  for (int i = t; i < KOFF * NVOX; i += stride) gatherT[i] = -1;
  for (int i = t; i < NVOX * CIN / 4; i += stride) {
    float4 f = ((const float4*)feats)[i];
    f16x4 h = {(_Float16)f.x, (_Float16)f.y, (_Float16)f.z, (_Float16)f.w};
    ((f16x4*)featsh)[i] = h;
  }
  if (t < 256) stats[t] = 0.f;
  if (t < CMID) x1h[NVOX * CMID + t] = (_Float16)0.f;
  if (t < CIN) featsh[NVOX * CIN + t] = (_Float16)0.f;
}

__global__ __launch_bounds__(256) void k_build(const int* __restrict__ rule_in,
                                               const int* __restrict__ rule_out,
                                               int* __restrict__ gatherT) {
  int e = blockIdx.x * 256 + threadIdx.x;
  if (e >= KOFF * NVOX) return;
  int k = e / NVOX;
  int dst = rule_out[e];
  if (dst < NVOX) gatherT[k * NVOX + dst] = rule_in[e];
}

// Build B-fragment-ordered fp16 weights.
// Fragment layout (16x16x32): lane l holds B[kk=(l>>4)*8+j][n], j=0..7; frag f covers n=f*16+(l&15).
// Flat index: ((pair_or_k*2 + f)*64 + l)*8 + j
__global__ __launch_bounds__(256) void k_prepw(const float* __restrict__ W1,
                                               const float* __restrict__ W2,
                                               _Float16* __restrict__ WB1,
                                               _Float16* __restrict__ WB2) {
  int e = blockIdx.x * 256 + threadIdx.x;
  if (e < NPAIR * 1024) {
    int j = e & 7, l = (e >> 3) & 63, f = (e >> 9) & 1, p = e >> 10;
    int kk = ((l >> 4) << 3) + j;           // 0..31
    int n = (f << 4) + (l & 15);
    int k = 2 * p + (kk >> 4);              // two offsets per pair
    int c = kk & 15;
    float v = (k < KOFF) ? W1[(k * CIN + c) * CMID + n] : 0.f;
    WB1[e] = (_Float16)v;
  }
  int e2 = e - NPAIR * 1024;
  if (e2 >= 0 && e2 < KOFF * 1024) {
    int j = e2 & 7, l = (e2 >> 3) & 63, f = (e2 >> 9) & 1, k = e2 >> 10;
    int kk = ((l >> 4) << 3) + j;
    int n = (f << 4) + (l & 15);
    WB2[e2] = (_Float16)W2[(k * CMID + kk) * COUT + n];
  }
}

// conv1 MFMA: wave = 16 rows, K=32 packs offsets (2p, 2p+1). Fused BN1 stats.
__global__ __launch_bounds__(1024, 8) void k_conv1m(const _Float16* __restrict__ featsh,
                                                    const int* __restrict__ gatherT,
                                                    const uint4* __restrict__ WB1,
                                                    _Float16* __restrict__ x1h,
                                                    float* __restrict__ gsums) {
  __shared__ uint4 wlds[NPAIR * 128];  // 28,672 B
  __shared__ float lsum[64];
  int tid = threadIdx.x;
  for (int i = tid; i < NPAIR * 128; i += 1024) wlds[i] = WB1[i];
  if (tid < 64) lsum[tid] = 0.f;
  __syncthreads();

  int lane = tid & 63, wave = tid >> 6;
  int q = lane >> 4, n = lane & 15;
  int rowbase = blockIdx.x * 256 + wave * 16;
  int row = rowbase + n;
  int rowc = (row < NVOX) ? row : (NVOX - 1);
  int kqoff = q >> 1;        // quads 0,1 -> offset 2p; quads 2,3 -> 2p+1
  int eoff = (q & 1) * 8;    // fp16 element offset within 16-ch row

  f32x4 c0 = {0.f, 0.f, 0.f, 0.f}, c1 = {0.f, 0.f, 0.f, 0.f};

  int kq0 = kqoff;
  int src = gatherT[kq0 * NVOX + rowc];
  unsigned s = ((unsigned)src >= NVOX) ? NVOX : (unsigned)src;
  f16x8 a = *(const f16x8*)(featsh + s * CIN + eoff);

#pragma unroll 1
  for (int p = 0; p < NPAIR; ++p) {
    int pn = (p + 1 < NPAIR) ? (p + 1) : p;
    int kq2 = 2 * pn + kqoff;
    if (kq2 > KOFF - 1) kq2 = KOFF - 1;   // p=13 quads 2,3: zero weights anyway
    int src2 = gatherT[kq2 * NVOX + rowc];
    unsigned s2 = ((unsigned)src2 >= NVOX) ? NVOX : (unsigned)src2;
    f16x8 a2 = *(const f16x8*)(featsh + s2 * CIN + eoff);
    f16x8 b0 = ((const f16x8*)wlds)[(p * 2 + 0) * 64 + lane];
    f16x8 b1 = ((const f16x8*)wlds)[(p * 2 + 1) * 64 + lane];
    c0 = __builtin_amdgcn_mfma_f32_16x16x32_f16(a, b0, c0, 0, 0, 0);
    c1 = __builtin_amdgcn_mfma_f32_16x16x32_f16(a, b1, c1, 0, 0, 0);
    a = a2;
  }

  // C-layout: col = lane&15 (=n), row m = q*4 + r. Store pre-BN fp16 + fused stats.
  float s0 = 0.f, sq0 = 0.f, s1 = 0.f, sq1 = 0.f;
#pragma unroll
  for (int r = 0; r < 4; ++r) {
    int grow = rowbase + q * 4 + r;
    float mk = (grow < NVOX) ? 1.f : 0.f;
    float v0 = c0[r] * mk, v1 = c1[r] * mk;
    s0 += v0; sq0 += v0 * v0; s1 += v1; sq1 += v1 * v1;
    if (grow < NVOX) {
      x1h[grow * CMID + n] = (_Float16)c0[r];
      x1h[grow * CMID + 16 + n] = (_Float16)c1[r];
    }
  }
#pragma unroll
  for (int msk = 16; msk < 64; msk <<= 1) {
    s0 += __shfl_xor(s0, msk, 64); sq0 += __shfl_xor(sq0, msk, 64);
    s1 += __shfl_xor(s1, msk, 64); sq1 += __shfl_xor(sq1, msk, 64);
  }
  if (lane < 16) {
    atomicAdd(&lsum[n], s0);       atomicAdd(&lsum[16 + n], s1);
    atomicAdd(&lsum[32 + n], sq0); atomicAdd(&lsum[48 + n], sq1);
  }
  __syncthreads();
  if (tid < 64) atomicAdd(&gsums[tid], lsum[tid]);
}

__global__ void k_finalize(const float* __restrict__ sums,
                           const float* __restrict__ gamma,
                           const float* __restrict__ beta,
                           float* __restrict__ ss) {
  int o = threadIdx.x;
  if (o < 32) {
    const float inv_n = 1.0f / (float)NVOX;
    float mu = sums[o] * inv_n;
    float var = sums[32 + o] * inv_n - mu * mu;
    float sc = gamma[o] * rsqrtf(var + EPSBN);
    ss[o] = sc;
    ss[32 + o] = beta[o] - mu * sc;
  }
}

// BN1+ReLU in place on fp16 x1h (rows < NVOX only; zero row untouched)
__global__ __launch_bounds__(256) void k_bnrelu1h(_Float16* __restrict__ x1h,
                                                  const float* __restrict__ ss) {
  int t = blockIdx.x * 256 + threadIdx.x;
  if (t >= NVOX * CMID / 8) return;
  f16x8* p = (f16x8*)x1h + t;
  int c = (t & 3) * 8;
  f16x8 v = *p;
#pragma unroll
  for (int i = 0; i < 8; ++i) {
    float x = (float)v[i];
    x = fmaf(x, ss[c + i], ss[32 + c + i]);
    v[i] = (_Float16)fmaxf(x, 0.f);
  }
  *p = v;
}

// conv2 MFMA: wave = 16 rows, K=32 = full CMID per offset. Fused BN2 stats. fp32 out (pre-BN).
__global__ __launch_bounds__(1024, 8) void k_conv2m(const _Float16* __restrict__ x1h,
                                                    const int* __restrict__ gatherT,
                                                    const uint4* __restrict__ WB2,
                                                    float* __restrict__ out,
                                                    float* __restrict__ gsums) {
  __shared__ uint4 wlds[KOFF * 128];  // 55,296 B
  __shared__ float lsum[64];
  int tid = threadIdx.x;
  for (int i = tid; i < KOFF * 128; i += 1024) wlds[i] = WB2[i];
  if (tid < 64) lsum[tid] = 0.f;
  __syncthreads();

  int lane = tid & 63, wave = tid >> 6;
  int q = lane >> 4, n = lane & 15;
  int rowbase = blockIdx.x * 256 + wave * 16;
  int row = rowbase + n;
  int rowc = (row < NVOX) ? row : (NVOX - 1);
  int eoff = q * 8;

  f32x4 c0 = {0.f, 0.f, 0.f, 0.f}, c1 = {0.f, 0.f, 0.f, 0.f};

  int src = gatherT[rowc];
  unsigned s = ((unsigned)src >= NVOX) ? NVOX : (unsigned)src;
  f16x8 a = *(const f16x8*)(x1h + s * CMID + eoff);

#pragma unroll 1
  for (int k = 0; k < KOFF; ++k) {
    int kn = (k + 1 < KOFF) ? (k + 1) : k;
    int src2 = gatherT[kn * NVOX + rowc];
    unsigned s2 = ((unsigned)src2 >= NVOX) ? NVOX : (unsigned)src2;
    f16x8 a2 = *(const f16x8*)(x1h + s2 * CMID + eoff);
    f16x8 b0 = ((const f16x8*)wlds)[(k * 2 + 0) * 64 + lane];
    f16x8 b1 = ((const f16x8*)wlds)[(k * 2 + 1) * 64 + lane];
    c0 = __builtin_amdgcn_mfma_f32_16x16x32_f16(a, b0, c0, 0, 0, 0);
    c1 = __builtin_amdgcn_mfma_f32_16x16x32_f16(a, b1, c1, 0, 0, 0);
    a = a2;
  }

  float s0 = 0.f, sq0 = 0.f, s1 = 0.f, sq1 = 0.f;
#pragma unroll
  for (int r = 0; r < 4; ++r) {
    int grow = rowbase + q * 4 + r;
    float mk = (grow < NVOX) ? 1.f : 0.f;
    float v0 = c0[r] * mk, v1 = c1[r] * mk;
    s0 += v0; sq0 += v0 * v0; s1 += v1; sq1 += v1 * v1;
    if (grow < NVOX) {
      out[grow * COUT + n] = c0[r];
      out[grow * COUT + 16 + n] = c1[r];
    }
  }
#pragma unroll
  for (int msk = 16; msk < 64; msk <<= 1) {
    s0 += __shfl_xor(s0, msk, 64); sq0 += __shfl_xor(sq0, msk, 64);
    s1 += __shfl_xor(s1, msk, 64); sq1 += __shfl_xor(sq1, msk, 64);
  }
  if (lane < 16) {
    atomicAdd(&lsum[n], s0);       atomicAdd(&lsum[16 + n], s1);
    atomicAdd(&lsum[32 + n], sq0); atomicAdd(&lsum[48 + n], sq1);
  }
  __syncthreads();
  if (tid < 64) atomicAdd(&gsums[tid], lsum[tid]);
}

// BN2+ReLU in place on fp32 out
__global__ __launch_bounds__(256) void k_bnrelu2(float* __restrict__ out,
                                                 const float* __restrict__ ss) {
  int t = blockIdx.x * 256 + threadIdx.x;
  if (t >= NVOX * COUT / 4) return;
  float4* p = (float4*)out + t;
  int c = (t & 7) * 4;
  float4 v = *p;
  v.x = fmaxf(fmaf(v.x, ss[c + 0], ss[32 + c + 0]), 0.f);
  v.y = fmaxf(fmaf(v.y, ss[c + 1], ss[32 + c + 1]), 0.f);
  v.z = fmaxf(fmaf(v.z, ss[c + 2], ss[32 + c + 2]), 0.f);
  v.w = fmaxf(fmaf(v.w, ss[c + 3], ss[32 + c + 3]), 0.f);
  *p = v;
}

extern "C" void kernel_launch(void* const* d_in, const int* in_sizes, int n_in,
                              void* d_out, int out_size, void* d_ws, size_t ws_size,
                              hipStream_t stream) {
  const float* feats  = (const float*)d_in[0];
  const float* W1     = (const float*)d_in[1];
  const float* gamma1 = (const float*)d_in[2];
  const float* beta1  = (const float*)d_in[3];
  const float* W2     = (const float*)d_in[4];
  const float* gamma2 = (const float*)d_in[5];
  const float* beta2  = (const float*)d_in[6];
  const int* rule_in  = (const int*)d_in[7];
  const int* rule_out = (const int*)d_in[8];
  float* out = (float*)d_out;

  int*       gatherT = (int*)d_ws;
  _Float16*  x1h     = (_Float16*)((char*)d_ws + OFF_X1H);
  _Float16*  featsh  = (_Float16*)((char*)d_ws + OFF_FH);
  _Float16*  WB1     = (_Float16*)((char*)d_ws + OFF_WB1);
  _Float16*  WB2     = (_Float16*)((char*)d_ws + OFF_WB2);
  float*     stats   = (float*)((char*)d_ws + OFF_ST);
  // stats: [0:64] sums1, [64:128] ss1, [128:192] sums2, [192:256] ss2

  k_init<<<2048, 256, 0, stream>>>(feats, gatherT, featsh, x1h, stats);
  k_build<<<(KOFF * NVOX + 255) / 256, 256, 0, stream>>>(rule_in, rule_out, gatherT);
  k_prepw<<<164, 256, 0, stream>>>(W1, W2, WB1, WB2);
  k_conv1m<<<782, 1024, 0, stream>>>(featsh, gatherT, (const uint4*)WB1, x1h, stats);
  k_finalize<<<1, 64, 0, stream>>>(stats, gamma1, beta1, stats + 64);
  k_bnrelu1h<<<(NVOX * CMID / 8 + 255) / 256, 256, 0, stream>>>(x1h, stats + 64);
  k_conv2m<<<782, 1024, 0, stream>>>(x1h, gatherT, (const uint4*)WB2, out, stats + 128);
  k_finalize<<<1, 64, 0, stream>>>(stats + 128, gamma2, beta2, stats + 192);
  k_bnrelu2<<<(NVOX * COUT / 4 + 255) / 256, 256, 0, stream>>>(out, stats + 192);
}

// Round 5
// 217.263 us; speedup vs baseline: 6.0866x; 1.0478x over previous
//
#include <hip/hip_runtime.h>

#define NVOX 200000
#define KOFF 27
#define CIN 16
#define CMID 32
#define COUT 32
#define EPSBN 1e-3f

typedef _Float16 f16x8 __attribute__((ext_vector_type(8)));
typedef _Float16 f16x4 __attribute__((ext_vector_type(4)));
typedef float f32x16 __attribute__((ext_vector_type(16)));

// ws layout (bytes):
//   [0, 21,600,000)              gatherT int32[KOFF][NVOX]  (-1 = none; init via memset 0xFF)
//   [21,600,000, 34,400,064)     x1h fp16[(NVOX+1)][32]  (conv1 out; BN1+ReLU in place; row NVOX = zeros)
//   [34,400,064, 40,800,096)     featsh fp16[(NVOX+1)][16] (row NVOX = zeros)
//   [40,800,096, 40,827,744)     WB1 fp16[27][64][8]   B-frags for 32x32x16 (K=16=CIN)
//   [40,827,744, 40,883,040)     WB2 fp16[27][2][64][8] B-frags (K=32 split in 2)
//   [40,883,040, +512)           stats: sums1[64] | sums2[64]
#define OFF_X1H 21600000
#define OFF_FH  34400064
#define OFF_WB1 40800096
#define OFF_WB2 40827744
#define OFF_ST  40883040

// Fused prep: rulebook scatter (gatherT pre-memset to -1), feats->fp16,
// weight fragging, zero rows.
// B-frag layout for 32x32x16: lane l holds B[kk=(l>>5)*8+j][n=l&31], j=0..7.
__global__ __launch_bounds__(256) void k_build(const int* __restrict__ rule_in,
                                               const int* __restrict__ rule_out,
                                               const float* __restrict__ feats,
                                               const float* __restrict__ W1,
                                               const float* __restrict__ W2,
                                               int* __restrict__ gatherT,
                                               _Float16* __restrict__ featsh,
                                               _Float16* __restrict__ WB1,
                                               _Float16* __restrict__ WB2,
                                               _Float16* __restrict__ x1h) {
  int e = blockIdx.x * 256 + threadIdx.x;
  if (e < KOFF * NVOX) {
    int k = e / NVOX;
    int dst = rule_out[e];
    if (dst < NVOX) gatherT[k * NVOX + dst] = rule_in[e];
  }
  if (e < NVOX * CIN / 4) {
    float4 f = ((const float4*)feats)[e];
    f16x4 h = {(_Float16)f.x, (_Float16)f.y, (_Float16)f.z, (_Float16)f.w};
    ((f16x4*)featsh)[e] = h;
  }
  if (e < KOFF * 512) {  // WB1: 13,824 elems
    int j = e & 7, l = (e >> 3) & 63, k = e >> 9;
    int kk = ((l >> 5) << 3) + j;          // 0..15 == input channel
    int n = l & 31;
    WB1[e] = (_Float16)W1[(k * CIN + kk) * CMID + n];
  }
  if (e < KOFF * 1024) {  // WB2: 27,648 elems, f selects K-half
    int j = e & 7, l = (e >> 3) & 63, f = (e >> 9) & 1, k = e >> 10;
    int kk = (f << 4) + ((l >> 5) << 3) + j;  // 0..31
    int n = l & 31;
    WB2[e] = (_Float16)W2[(k * CMID + kk) * COUT + n];
  }
  if (e < CMID) x1h[(size_t)NVOX * CMID + e] = (_Float16)0.f;
  if (e < CIN) featsh[(size_t)NVOX * CIN + e] = (_Float16)0.f;
}

// conv1: 32 rows/wave, 1 MFMA (32x32x16, K=16=CIN) per offset. Fused BN1 stats.
__global__ __launch_bounds__(512, 4) void k_conv1m(const _Float16* __restrict__ featsh,
                                                   const int* __restrict__ gatherT,
                                                   const uint4* __restrict__ WB1,
                                                   _Float16* __restrict__ x1h,
                                                   float* __restrict__ gsums) {
  __shared__ uint4 wlds[KOFF * 64];  // 27,648 B
  __shared__ float lsum[64];
  int tid = threadIdx.x;
  for (int i = tid; i < KOFF * 64; i += 512) wlds[i] = WB1[i];
  if (tid < 64) lsum[tid] = 0.f;
  __syncthreads();

  int lane = tid & 63, wave = tid >> 6;
  int m = lane & 31, khalf = lane >> 5;
  int rowbase = blockIdx.x * 256 + wave * 32;
  int row = rowbase + m;
  int rowc = (row < NVOX) ? row : (NVOX - 1);

  int idx[KOFF];
#pragma unroll
  for (int k = 0; k < KOFF; ++k) idx[k] = gatherT[k * NVOX + rowc];

  f32x16 c;
#pragma unroll
  for (int i = 0; i < 16; ++i) c[i] = 0.f;

#pragma unroll
  for (int k = 0; k < KOFF; ++k) {
    unsigned s = ((unsigned)idx[k] < (unsigned)NVOX) ? (unsigned)idx[k] : (unsigned)NVOX;
    f16x8 a = *(const f16x8*)(featsh + (size_t)s * CIN + (khalf << 3));
    f16x8 b = ((const f16x8*)wlds)[k * 64 + lane];
    c = __builtin_amdgcn_mfma_f32_32x32x16_f16(a, b, c, 0, 0, 0);
  }

  // C layout: col = lane&31 (= channel m), row = (r&3) + 8*(r>>2) + 4*khalf
  float s0 = 0.f, q0 = 0.f;
#pragma unroll
  for (int r = 0; r < 16; ++r) {
    int grow = rowbase + (r & 3) + ((r >> 2) << 3) + (khalf << 2);
    float mk = (grow < NVOX) ? 1.f : 0.f;
    float v = c[r] * mk;
    s0 += v; q0 += v * v;
    if (grow < NVOX) x1h[(size_t)grow * CMID + m] = (_Float16)c[r];
  }
  s0 += __shfl_xor(s0, 32, 64);
  q0 += __shfl_xor(q0, 32, 64);
  if (lane < 32) {
    atomicAdd(&lsum[m], s0);
    atomicAdd(&lsum[32 + m], q0);
  }
  __syncthreads();
  if (tid < 64) atomicAdd(&gsums[tid], lsum[tid]);
}

// BN1+ReLU in place on fp16 x1h, finalize fused (reads raw sums)
__global__ __launch_bounds__(256) void k_bnrelu1h(_Float16* __restrict__ x1h,
                                                  const float* __restrict__ sums,
                                                  const float* __restrict__ gamma,
                                                  const float* __restrict__ beta) {
  int t = blockIdx.x * 256 + threadIdx.x;
  if (t >= NVOX * CMID / 8) return;
  int c = (t & 3) * 8;
  const float inv_n = 1.0f / (float)NVOX;
  float sc[8], sh[8];
#pragma unroll
  for (int i = 0; i < 8; ++i) {
    float mu = sums[c + i] * inv_n;
    float var = sums[32 + c + i] * inv_n - mu * mu;
    float s = gamma[c + i] * rsqrtf(var + EPSBN);
    sc[i] = s; sh[i] = beta[c + i] - mu * s;
  }
  f16x8* p = (f16x8*)x1h + t;
  f16x8 v = *p;
#pragma unroll
  for (int i = 0; i < 8; ++i) {
    float x = fmaf((float)v[i], sc[i], sh[i]);
    v[i] = (_Float16)fmaxf(x, 0.f);
  }
  *p = v;
}

// conv2: 32 rows/wave, 2 MFMAs (K=32) per offset. Fused BN2 stats. fp32 pre-BN out.
__global__ __launch_bounds__(512, 4) void k_conv2m(const _Float16* __restrict__ x1h,
                                                   const int* __restrict__ gatherT,
                                                   const uint4* __restrict__ WB2,
                                                   float* __restrict__ out,
                                                   float* __restrict__ gsums) {
  __shared__ uint4 wlds[KOFF * 128];  // 55,296 B
  __shared__ float lsum[64];
  int tid = threadIdx.x;
  for (int i = tid; i < KOFF * 128; i += 512) wlds[i] = WB2[i];
  if (tid < 64) lsum[tid] = 0.f;
  __syncthreads();

  int lane = tid & 63, wave = tid >> 6;
  int m = lane & 31, khalf = lane >> 5;
  int rowbase = blockIdx.x * 256 + wave * 32;
  int row = rowbase + m;
  int rowc = (row < NVOX) ? row : (NVOX - 1);

  int idx[KOFF];
#pragma unroll
  for (int k = 0; k < KOFF; ++k) idx[k] = gatherT[k * NVOX + rowc];

  f32x16 c;
#pragma unroll
  for (int i = 0; i < 16; ++i) c[i] = 0.f;

#pragma unroll
  for (int k = 0; k < KOFF; ++k) {
    unsigned s = ((unsigned)idx[k] < (unsigned)NVOX) ? (unsigned)idx[k] : (unsigned)NVOX;
    const _Float16* rp = x1h + (size_t)s * CMID + (khalf << 3);
    f16x8 a0 = *(const f16x8*)(rp);
    f16x8 a1 = *(const f16x8*)(rp + 16);
    f16x8 b0 = ((const f16x8*)wlds)[(k * 2 + 0) * 64 + lane];
    f16x8 b1 = ((const f16x8*)wlds)[(k * 2 + 1) * 64 + lane];
    c = __builtin_amdgcn_mfma_f32_32x32x16_f16(a0, b0, c, 0, 0, 0);
    c = __builtin_amdgcn_mfma_f32_32x32x16_f16(a1, b1, c, 0, 0, 0);
  }

  float s0 = 0.f, q0 = 0.f;
#pragma unroll
  for (int r = 0; r < 16; ++r) {
    int grow = rowbase + (r & 3) + ((r >> 2) << 3) + (khalf << 2);
    float mk = (grow < NVOX) ? 1.f : 0.f;
    float v = c[r] * mk;
    s0 += v; q0 += v * v;
    if (grow < NVOX) out[(size_t)grow * COUT + m] = c[r];
  }
  s0 += __shfl_xor(s0, 32, 64);
  q0 += __shfl_xor(q0, 32, 64);
  if (lane < 32) {
    atomicAdd(&lsum[m], s0);
    atomicAdd(&lsum[32 + m], q0);
  }
  __syncthreads();
  if (tid < 64) atomicAdd(&gsums[tid], lsum[tid]);
}

// BN2+ReLU in place on fp32 out, finalize fused
__global__ __launch_bounds__(256) void k_bnrelu2(float* __restrict__ out,
                                                 const float* __restrict__ sums,
                                                 const float* __restrict__ gamma,
                                                 const float* __restrict__ beta) {
  int t = blockIdx.x * 256 + threadIdx.x;
  if (t >= NVOX * COUT / 4) return;
  int c = (t & 7) * 4;
  const float inv_n = 1.0f / (float)NVOX;
  float sc[4], sh[4];
#pragma unroll
  for (int i = 0; i < 4; ++i) {
    float mu = sums[c + i] * inv_n;
    float var = sums[32 + c + i] * inv_n - mu * mu;
    float s = gamma[c + i] * rsqrtf(var + EPSBN);
    sc[i] = s; sh[i] = beta[c + i] - mu * s;
  }
  float4* p = (float4*)out + t;
  float4 v = *p;
  v.x = fmaxf(fmaf(v.x, sc[0], sh[0]), 0.f);
  v.y = fmaxf(fmaf(v.y, sc[1], sh[1]), 0.f);
  v.z = fmaxf(fmaf(v.z, sc[2], sh[2]), 0.f);
  v.w = fmaxf(fmaf(v.w, sc[3], sh[3]), 0.f);
  *p = v;
}

extern "C" void kernel_launch(void* const* d_in, const int* in_sizes, int n_in,
                              void* d_out, int out_size, void* d_ws, size_t ws_size,
                              hipStream_t stream) {
  const float* feats  = (const float*)d_in[0];
  const float* W1     = (const float*)d_in[1];
  const float* gamma1 = (const float*)d_in[2];
  const float* beta1  = (const float*)d_in[3];
  const float* W2     = (const float*)d_in[4];
  const float* gamma2 = (const float*)d_in[5];
  const float* beta2  = (const float*)d_in[6];
  const int* rule_in  = (const int*)d_in[7];
  const int* rule_out = (const int*)d_in[8];
  float* out = (float*)d_out;

  int*       gatherT = (int*)d_ws;
  _Float16*  x1h     = (_Float16*)((char*)d_ws + OFF_X1H);
  _Float16*  featsh  = (_Float16*)((char*)d_ws + OFF_FH);
  _Float16*  WB1     = (_Float16*)((char*)d_ws + OFF_WB1);
  _Float16*  WB2     = (_Float16*)((char*)d_ws + OFF_WB2);
  float*     stats   = (float*)((char*)d_ws + OFF_ST);
  // stats: [0:64] sums1, [64:128] sums2

  hipMemsetAsync(gatherT, 0xFF, (size_t)KOFF * NVOX * 4, stream);
  hipMemsetAsync(stats, 0, 128 * 4, stream);
  k_build<<<(KOFF * NVOX + 255) / 256, 256, 0, stream>>>(
      rule_in, rule_out, feats, W1, W2, gatherT, featsh, WB1, WB2, x1h);
  k_conv1m<<<782, 512, 0, stream>>>(featsh, gatherT, (const uint4*)WB1, x1h, stats);
  k_bnrelu1h<<<(NVOX * CMID / 8 + 255) / 256, 256, 0, stream>>>(x1h, stats, gamma1, beta1);
  k_conv2m<<<782, 512, 0, stream>>>(x1h, gatherT, (const uint4*)WB2, out, stats + 64);
  k_bnrelu2<<<(NVOX * COUT / 4 + 255) / 256, 256, 0, stream>>>(out, stats + 64, gamma2, beta2);
}